// Round 8
// baseline (116.218 us; speedup 1.0000x reference)
//
#include <hip/hip_runtime.h>

#define IN_F 1024
#define OUT_F 1024
#define NTOK 32768
#define BM 128
#define BN 128
#define BK 64
#define KT (IN_F / BK)  // 16 K-tiles

typedef __bf16 bf16;
typedef __bf16 bf16x4 __attribute__((ext_vector_type(4)));
typedef __bf16 bf16x8 __attribute__((ext_vector_type(8)));
typedef float f32x4 __attribute__((ext_vector_type(4)));

// ---------------------------------------------------------------------------
// Kernel 1: build patched bf16 weight W' (validated rounds 1-7).
// ---------------------------------------------------------------------------
__global__ void build_wp(const float* __restrict__ W,
                         const int* __restrict__ rows,
                         const int* __restrict__ srcs,
                         const int* __restrict__ clones,
                         bf16* __restrict__ Wp) {
  const int r = blockIdx.x;
  const int row = rows[r];
  const int s = srcs[r];
  const int c0 = clones[3 * r + 0];
  const int c1 = clones[3 * r + 1];
  const int c2 = clones[3 * r + 2];
  const float* wr = W + (size_t)row * IN_F;
  const float fixv = 0.25f * (wr[s] + wr[c0] + wr[c1] + wr[c2]);

  const int col = threadIdx.x * 4;
  f32x4 v = *reinterpret_cast<const f32x4*>(wr + col);
  bf16x4 o;
#pragma unroll
  for (int j = 0; j < 4; ++j) {
    const int c = col + j;
    float f = v[j];
    if (c == c0 || c == c1 || c == c2) f = 0.0f;
    if (c == s) f = fixv;
    o[j] = (bf16)f;
  }
  *reinterpret_cast<bf16x4*>(Wp + (size_t)row * IN_F + col) = o;
}

// ---------------------------------------------------------------------------
// Kernel 2: out = X @ W'^T + bias.
// 128x128 tile, 4 waves (2x2, per-wave 64x64), BK=64, double-buffered 64KB
// STATIC LDS -> 2 blocks/CU. Thesis (m114): two co-resident blocks with
// desynchronized barriers keep the LDS port + MFMA pipe busy through each
// other's drain windows — the verified mechanism my 1-block/CU schedules
// (rounds 4/7, both ~21-23% MfmaUtil) could not exploit.
// One __syncthreads per K-tile; NO hand vmcnt / sched_barrier (m141).
// A (fp32): reg-staged 2 K-tiles deep (static avA/avB rotation, rule 20)
//           -> cvt -> swizzled ds_write one tile ahead.
// B (bf16 Wp, L2-resident): global_load_lds one tile ahead, linear dest +
//           pre-swizzled global source (rounds 4-7: 0 bank conflicts).
// ---------------------------------------------------------------------------
__global__ __launch_bounds__(256, 2) void gemm_rewire(
    const float* __restrict__ X, const bf16* __restrict__ Wp,
    const float* __restrict__ bias, float* __restrict__ out) {
  __shared__ __align__(16) bf16 lA[2][BM * BK];  // 16 KB each
  __shared__ __align__(16) bf16 lB[2][BN * BK];  // 16 KB each

  const int tid = threadIdx.x;
  const int lane = tid & 63;
  const int w = tid >> 6;   // 0..3
  const int wrow = w >> 1;  // 0..1 (64-row half)
  const int wcol = w & 1;   // 0..1 (64-col half)

  // XCD-grouped decode: 2048 blocks = 8 XCD slots x 256 seq; per XCD the 8
  // bn-sharers of one X-panel are consecutive -> panel fetched once from HBM.
  const int bid = blockIdx.x;                // 0..2047
  const int seq = bid >> 3;                  // 0..255
  const int bm = (bid & 7) + 8 * (seq >> 3); // 0..255
  const int bn = seq & 7;                    // 0..7

  // --- A staging: per jj (0..3) thread covers row (tid>>3)+jj*32,
  // 8 fp32 at col (tid&7)*8 (256B-contiguous per row across 8 lanes).
  const float* gA = X + ((size_t)bm * BM + (tid >> 3)) * IN_F + (tid & 7) * 8;
  // ds_write: row*128B + swizzled 16B slot ((tid&7) ^ (row&7)); jj adds 4096B.
  const int awbyte =
      ((tid >> 3) << 7) + ((((tid & 7) ^ ((tid >> 3) & 7))) << 4);

  // --- B staging: linear gload_lds dest; pre-swizzled global source.
  // issue i: LDS row = w*32 + i*8 + (lane>>3), phys slot = lane&7.
  const bf16* gB = Wp + ((size_t)bn * BN + w * 32 + (lane >> 3)) * IN_F +
                   (((lane & 7) ^ ((lane >> 3) & 7)) * 8);

  // --- accumulators preloaded with bias (C/D col = lane&15)
  f32x4 acc[4][4];
#pragma unroll
  for (int n = 0; n < 4; ++n) {
    const float bv = bias[bn * BN + wcol * 64 + n * 16 + (lane & 15)];
#pragma unroll
    for (int m = 0; m < 4; ++m) acc[m][n] = (f32x4){bv, bv, bv, bv};
  }

  // --- fragment read geometry (validated swizzle: slot^(row&7), 128B rows)
  const int rl = lane & 15;
  const int rx = rl & 7;
  const int arow0 = wrow * 64 + rl;  // + m*16
  const int brow0 = wcol * 64 + rl;  // + n*16
  const int sl0 = lane >> 4;         // + kk*4

  f32x4 avA[8], avB[8];

  auto issueA = [&](int t, f32x4 (&v)[8]) {
#pragma unroll
    for (int jj = 0; jj < 4; ++jj) {
      const float* p = gA + (size_t)jj * 32 * IN_F + (size_t)t * BK;
      v[2 * jj] = *reinterpret_cast<const f32x4*>(p);
      v[2 * jj + 1] = *reinterpret_cast<const f32x4*>(p + 4);
    }
  };
  auto writeA = [&](const f32x4 (&v)[8], int buf) {
    char* base = (char*)lA[buf];
#pragma unroll
    for (int jj = 0; jj < 4; ++jj) {
      bf16x8 o;
#pragma unroll
      for (int q = 0; q < 4; ++q) {
        o[q] = (bf16)v[2 * jj][q];
        o[4 + q] = (bf16)v[2 * jj + 1][q];
      }
      *reinterpret_cast<bf16x8*>(base + jj * 4096 + awbyte) = o;
    }
  };
  auto issueB = [&](int t, int buf) {
    const bf16* g = gB + (size_t)t * BK;
#pragma unroll
    for (int i = 0; i < 4; ++i) {
      char* dst = (char*)lB[buf] + w * 4096 + i * 1024;  // wave-uniform base
      __builtin_amdgcn_global_load_lds(
          (const __attribute__((address_space(1))) void*)(g +
                                                          (size_t)i * 8 * IN_F),
          (__attribute__((address_space(3))) void*)dst, 16, 0, 0);
    }
  };
  auto compute = [&](int buf) {
    const char* A = (const char*)lA[buf];
    const char* B = (const char*)lB[buf];
#pragma unroll
    for (int kk = 0; kk < 2; ++kk) {
      const int so = (((kk * 4 + sl0) ^ rx) << 4);
      bf16x8 af[4], bfr[4];
#pragma unroll
      for (int m = 0; m < 4; ++m)
        af[m] =
            *reinterpret_cast<const bf16x8*>(A + (arow0 + m * 16) * 128 + so);
#pragma unroll
      for (int n = 0; n < 4; ++n)
        bfr[n] =
            *reinterpret_cast<const bf16x8*>(B + (brow0 + n * 16) * 128 + so);
#pragma unroll
      for (int m = 0; m < 4; ++m)
#pragma unroll
        for (int n = 0; n < 4; ++n)
          acc[m][n] = __builtin_amdgcn_mfma_f32_16x16x32_bf16(
              af[m], bfr[n], acc[m][n], 0, 0, 0);
    }
  };

  // --- prologue: A(0),A(1) in regs; B(0) staged; A(0) -> LDS.
  issueA(0, avA);
  issueA(1, avB);
  issueB(0, 0);
  writeA(avA, 0);   // exact vmcnt: waits avA only
  __syncthreads();  // drains B(0); tile 0 ready

  // --- main loop: 2 tiles per iteration (static avA/avB rotation, rule 20).
#pragma unroll 1
  for (int i = 0; i < KT / 2; ++i) {
    const int t = 2 * i;
    // tile t (buf 0)
    if (t + 2 < KT) issueA(t + 2, avA);  // avA already consumed
    issueB(t + 1, 1);
    writeA(avB, 1);  // exact vmcnt: waits avB, leaves avA + B in flight
    compute(0);
    __syncthreads();
    // tile t+1 (buf 1)
    if (t + 3 < KT) issueA(t + 3, avB);
    if (t + 2 < KT) {
      issueB(t + 2, 0);
      writeA(avA, 0);
    }
    compute(1);
    __syncthreads();
  }

  // --- epilogue: C/D layout col = lane&15, row = (lane>>4)*4 + i
  const int orow0 = bm * BM + wrow * 64 + (lane >> 4) * 4;
  const int ocol = bn * BN + wcol * 64 + (lane & 15);
#pragma unroll
  for (int m = 0; m < 4; ++m) {
#pragma unroll
    for (int n = 0; n < 4; ++n) {
      const f32x4 v = acc[m][n];
      const size_t base = (size_t)(orow0 + m * 16) * OUT_F + (ocol + n * 16);
#pragma unroll
      for (int i2 = 0; i2 < 4; ++i2) out[base + (size_t)i2 * OUT_F] = v[i2];
    }
  }
}

// ---------------------------------------------------------------------------
extern "C" void kernel_launch(void* const* d_in, const int* in_sizes, int n_in,
                              void* d_out, int out_size, void* d_ws,
                              size_t ws_size, hipStream_t stream) {
  const float* x = (const float*)d_in[0];
  const float* weight = (const float*)d_in[1];
  const float* bias = (const float*)d_in[2];
  const int* rrows = (const int*)d_in[3];
  const int* rsrc = (const int*)d_in[4];
  const int* rclones = (const int*)d_in[5];
  float* out = (float*)d_out;
  bf16* Wp = (bf16*)d_ws;  // 2 MB scratch

  build_wp<<<dim3(OUT_F), dim3(256), 0, stream>>>(weight, rrows, rsrc, rclones,
                                                  Wp);
  gemm_rewire<<<dim3((NTOK / BM) * (OUT_F / BN)), dim3(256), 0, stream>>>(
      x, Wp, bias, out);
}

// Round 9
// 110.214 us; speedup vs baseline: 1.0545x; 1.0545x over previous
//
#include <hip/hip_runtime.h>

#define IN_F 1024
#define OUT_F 1024
#define NTOK 32768
#define BM 256
#define BN 256
#define BK 64
#define KT (IN_F / BK)  // 16 K-tiles

typedef __bf16 bf16;
typedef __bf16 bf16x4 __attribute__((ext_vector_type(4)));
typedef __bf16 bf16x8 __attribute__((ext_vector_type(8)));
typedef float f32x4 __attribute__((ext_vector_type(4)));
typedef float f32x16 __attribute__((ext_vector_type(16)));

// ---------------------------------------------------------------------------
// Kernel 1: build patched bf16 weight W' (validated rounds 1-8).
// ---------------------------------------------------------------------------
__global__ void build_wp(const float* __restrict__ W,
                         const int* __restrict__ rows,
                         const int* __restrict__ srcs,
                         const int* __restrict__ clones,
                         bf16* __restrict__ Wp) {
  const int r = blockIdx.x;
  const int row = rows[r];
  const int s = srcs[r];
  const int c0 = clones[3 * r + 0];
  const int c1 = clones[3 * r + 1];
  const int c2 = clones[3 * r + 2];
  const float* wr = W + (size_t)row * IN_F;
  const float fixv = 0.25f * (wr[s] + wr[c0] + wr[c1] + wr[c2]);

  const int col = threadIdx.x * 4;
  f32x4 v = *reinterpret_cast<const f32x4*>(wr + col);
  bf16x4 o;
#pragma unroll
  for (int j = 0; j < 4; ++j) {
    const int c = col + j;
    float f = v[j];
    if (c == c0 || c == c1 || c == c2) f = 0.0f;
    if (c == s) f = fixv;
    o[j] = (bf16)f;
  }
  *reinterpret_cast<bf16x4*>(Wp + (size_t)row * IN_F + col) = o;
}

// ---------------------------------------------------------------------------
// Kernel 2: out = X @ W'^T + bias — round-4 structure (best measured) with
// 32x32x16 MFMA instead of 16x16x32:
//   * µbench rate 2382 vs 2075 TF (+15%), half the MFMA instructions per
//     wave-tile (32 vs 64 per K-tile) -> less issue pressure vs A-path,
//   * verified C/D layout (m74/m101): col=lane&31, row=(reg&3)+8*(reg>>2)
//     +4*(lane>>5); A/B frag: row=lane&31, k=(lane>>5)*8 (same K-chunk
//     formula as the verified 16x16x32 mapping),
//   * epilogue stores coalesce at 128B per 32-lane group (was 64B).
// Everything else identical to round 4: 256x256 tile, 8 waves (2Mx4N,
// per-wave 128x64), BK=64, double-buffered 128KB dynamic LDS, ONE barrier
// per K-tile, no hand waits; A fp32 reg-staged->cvt->swizzled ds_write;
// B via global_load_lds (linear dest + pre-swizzled source, 0 conflicts);
// XCD-grouped grid.
// ---------------------------------------------------------------------------
__global__ __launch_bounds__(512, 2) void gemm_rewire(
    const float* __restrict__ X, const bf16* __restrict__ Wp,
    const float* __restrict__ bias, float* __restrict__ out) {
  extern __shared__ __align__(16) char smem[];  // 128KB: A0 A1 B0 B1 (32KB ea)

  const int tid = threadIdx.x;
  const int lane = tid & 63;
  const int w = tid >> 6;   // 0..7
  const int wrow = w >> 2;  // 0..1  (128-row half of A)
  const int wcol = w & 3;   // 0..3  (64-col quarter of B)

  // XCD-grouped decode (validated: X panel fetched once per XCD).
  const int bid = blockIdx.x;                // 0..511
  const int sq = bid >> 3;                   // 0..63
  const int bm = (bid & 7) + 8 * (sq >> 2);  // 0..127
  const int bn = sq & 3;                     // 0..3

  // --- A staging (r4-identical): thread owns rows (tid>>3)+j*64, fp32 cols
  // (tid&7)*8..+8; swizzled 16B write slot = (tid&7) ^ (row&7).
  const float* gA = X + ((size_t)bm * BM + (tid >> 3)) * IN_F + (tid & 7) * 8;
  const int awbyte =
      ((tid >> 3) << 7) + ((((tid & 7) ^ ((tid >> 3) & 7))) << 4);

  // --- B staging (r4-identical): linear gload_lds dest; pre-swizzled source.
  const bf16* gB = Wp + ((size_t)bn * BN + w * 8 + (lane >> 3)) * IN_F +
                   (((lane & 7) ^ ((lane >> 3) & 7)) * 8);

  // --- accumulators preloaded with bias (32x32 C/D: col = lane&31)
  f32x16 acc[4][2];
#pragma unroll
  for (int nf = 0; nf < 2; ++nf) {
    const float bv = bias[bn * BN + wcol * 64 + nf * 32 + (lane & 31)];
#pragma unroll
    for (int mf = 0; mf < 4; ++mf)
#pragma unroll
      for (int r = 0; r < 16; ++r) acc[mf][nf][r] = bv;
  }

  // --- fragment read geometry (32x32x16): lane reads row = base + lane&31,
  // k = ks*16 + (lane>>5)*8 -> 16B slot = ks*2 + (lane>>5), XOR row&7.
  const int rl = lane & 31;
  const int rx = rl & 7;
  const int arow0 = wrow * 128 + rl;  // + mf*32
  const int brow0 = wcol * 64 + rl;   // + nf*32
  const int sl0 = lane >> 5;          // + ks*2

  f32x4 av[8];

  auto issueA = [&](int t) {
#pragma unroll
    for (int j = 0; j < 4; ++j) {
      const float* p = gA + (size_t)j * 64 * IN_F + (size_t)t * BK;
      av[2 * j] = *reinterpret_cast<const f32x4*>(p);
      av[2 * j + 1] = *reinterpret_cast<const f32x4*>(p + 4);
    }
  };
  auto writeA = [&](int buf) {
    char* base = smem + buf * 32768;
#pragma unroll
    for (int j = 0; j < 4; ++j) {
      bf16x8 o;
#pragma unroll
      for (int q = 0; q < 4; ++q) {
        o[q] = (bf16)av[2 * j][q];
        o[4 + q] = (bf16)av[2 * j + 1][q];
      }
      *reinterpret_cast<bf16x8*>(base + j * 8192 + awbyte) = o;
    }
  };
  auto issueB = [&](int t, int buf) {
    const bf16* g = gB + (size_t)t * BK;
    char* dst0 = smem + 65536 + buf * 32768 + w * 1024;  // wave-uniform base
#pragma unroll
    for (int i = 0; i < 4; ++i) {
      __builtin_amdgcn_global_load_lds(
          (const __attribute__((address_space(1))) void*)(g +
                                                          (size_t)i * 64 * IN_F),
          (__attribute__((address_space(3))) void*)(dst0 + i * 8192), 16, 0, 0);
    }
  };
  auto compute = [&](int buf) {
    const char* A = smem + buf * 32768;
    const char* B = smem + 65536 + buf * 32768;
#pragma unroll
    for (int ks = 0; ks < 4; ++ks) {
      const int so = (((ks * 2 + sl0) ^ rx) << 4);
      bf16x8 af[4], bfr[2];
#pragma unroll
      for (int mf = 0; mf < 4; ++mf)
        af[mf] =
            *reinterpret_cast<const bf16x8*>(A + (arow0 + mf * 32) * 128 + so);
#pragma unroll
      for (int nf = 0; nf < 2; ++nf)
        bfr[nf] =
            *reinterpret_cast<const bf16x8*>(B + (brow0 + nf * 32) * 128 + so);
      __builtin_amdgcn_s_setprio(1);
#pragma unroll
      for (int mf = 0; mf < 4; ++mf)
#pragma unroll
        for (int nf = 0; nf < 2; ++nf)
          acc[mf][nf] = __builtin_amdgcn_mfma_f32_32x32x16_bf16(
              af[mf], bfr[nf], acc[mf][nf], 0, 0, 0);
      __builtin_amdgcn_s_setprio(0);
    }
  };

  // --- prologue: stage tile 0 into buffer 0 (r4-identical)
  issueA(0);
  issueB(0, 0);
  writeA(0);        // compiler inserts exact vmcnt wait for av
  __syncthreads();  // drains B(0) gloads + ds_writes

  // --- main loop: one barrier per K-tile (r4-identical)
  for (int t = 0; t < KT; ++t) {
    const int db = t & 1;
    const bool more = (t + 1) < KT;
    if (more) {
      issueA(t + 1);          // 8 dwordx4 -> regs (in flight through compute)
      issueB(t + 1, db ^ 1);  // 4 gload_lds -> other buffer
      __builtin_amdgcn_sched_barrier(0);
    }
    compute(db);
    if (more) {
      __builtin_amdgcn_sched_barrier(0);  // keep MFMAs above the cvt/write
      writeA(db ^ 1);   // waits A-loads only, leaves B gloads in flight
      __syncthreads();  // tile boundary (loads landed under compute)
    }
  }

  // --- epilogue: 32x32 C/D layout col = lane&31,
  // row = (r&3) + 8*(r>>2) + 4*(lane>>5). 32 lanes/row -> 128B stores.
  const int ocol = bn * BN + wcol * 64 + (lane & 31);
  const int orow0 = bm * BM + wrow * 128 + 4 * (lane >> 5);
#pragma unroll
  for (int mf = 0; mf < 4; ++mf) {
#pragma unroll
    for (int nf = 0; nf < 2; ++nf) {
      const f32x16 v = acc[mf][nf];
#pragma unroll
      for (int r = 0; r < 16; ++r) {
        const int row = orow0 + mf * 32 + (r & 3) + 8 * (r >> 2);
        out[(size_t)row * OUT_F + ocol + nf * 32] = v[r];
      }
    }
  }
}

// ---------------------------------------------------------------------------
extern "C" void kernel_launch(void* const* d_in, const int* in_sizes, int n_in,
                              void* d_out, int out_size, void* d_ws,
                              size_t ws_size, hipStream_t stream) {
  const float* x = (const float*)d_in[0];
  const float* weight = (const float*)d_in[1];
  const float* bias = (const float*)d_in[2];
  const int* rrows = (const int*)d_in[3];
  const int* rsrc = (const int*)d_in[4];
  const int* rclones = (const int*)d_in[5];
  float* out = (float*)d_out;
  bf16* Wp = (bf16*)d_ws;  // 2 MB scratch

  (void)hipFuncSetAttribute((const void*)gemm_rewire,
                            hipFuncAttributeMaxDynamicSharedMemorySize, 131072);

  build_wp<<<dim3(OUT_F), dim3(256), 0, stream>>>(weight, rrows, rsrc, rclones,
                                                  Wp);
  gemm_rewire<<<dim3((NTOK / BM) * (OUT_F / BN)), dim3(512), 131072, stream>>>(
      x, Wp, bias, out);
}